// Round 1
// baseline (1950.493 us; speedup 1.0000x reference)
//
#include <hip/hip_runtime.h>
#include <stdint.h>
#include <math.h>

#define T_ 4
#define B_ 16
#define C_ 256
#define N_ 1024
#define HD_ 1024
#define HEADS_ 8
#define DH_ 32

typedef float v2f  __attribute__((ext_vector_type(2)));
typedef float f4v  __attribute__((ext_vector_type(4)));
typedef float f8v  __attribute__((ext_vector_type(8)));
typedef float f16v __attribute__((ext_vector_type(16)));

// v_pk_fma_f32 with op_sel broadcasting one 32-bit half of src0 (an SGPR pair)
// to both halves. Two independent IEEE fp32 FMAs; bit-exact per-output chains.
#define PKLs(a, w, x) asm volatile("v_pk_fma_f32 %0, %1, %2, %0 op_sel:[0,0,0] op_sel_hi:[0,1,1]" : "+v"(a) : "s"(w), "v"(x))
#define PKHs(a, w, x) asm volatile("v_pk_fma_f32 %0, %1, %2, %0 op_sel:[1,0,0] op_sel_hi:[1,1,1]" : "+v"(a) : "s"(w), "v"(x))

// Wt[k][ooff+o] = W[o][k].  W: [O][K] row-major.  grid (K/32, O/32), 256 thr.
__global__ __launch_bounds__(256)
void transW(const float* __restrict__ W, float* __restrict__ Wt,
            int O, int K, int ostride, int ooff)
{
  __shared__ float tl[32][33];
  int k0 = blockIdx.x*32, o0 = blockIdx.y*32;
  int tid = threadIdx.x;
  int a = tid & 31, bq = tid >> 5;
#pragma unroll
  for (int i=0;i<4;i++)
    tl[bq+8*i][a] = W[(size_t)(o0+bq+8*i)*K + k0 + a];
  __syncthreads();
#pragma unroll
  for (int i=0;i<4;i++)
    Wt[(size_t)(k0+bq+8*i)*ostride + ooff + o0 + a] = tl[a][bq+8*i];
}

__global__ __launch_bounds__(256)
void packBn3(const float* __restrict__ a, const float* __restrict__ b,
             const float* __restrict__ c, float* __restrict__ o)
{
  int i = blockIdx.x*256 + threadIdx.x;            // 0..1023 = [4][256]
  int r = i >> 8, ci = i & 255;
  o[(size_t)r*768 + ci]       = a[i];
  o[(size_t)r*768 + 256 + ci] = b[i];
  o[(size_t)r*768 + 512 + ci] = c[i];
}

template<int UO> struct WReg;
template<> struct WReg<16> { union { f16v v; v2f p[8]; }; };
template<> struct WReg<8>  { union { f8v  v; v2f p[4]; }; };

template<int UO>
__device__ __forceinline__ void wload(WReg<UO>& wr, const float* wp){
  if constexpr (UO==16)
    asm volatile("s_load_dwordx16 %0, %1, 0x0" : "=s"(wr.v) : "s"(wp));
  else
    asm volatile("s_load_dwordx8 %0, %1, 0x0" : "=s"(wr.v) : "s"(wp));
}

// Y = Wt^T @ X (+bias) -> BN -> LIF, t-loop inside block (LIF state in regs).
// Wave-uniform o-tile (UO rows per wave, W from SGPR via s_load), per-lane
// 4 consecutive n.  X staged to LDS via global_load_lds, double-buffered.
// Per k: 1 s_load (scalar pipe) + 1 ds_read_b128/b32 per lane + 32/16 pk_fma.
// Numeric contract: per output, strictly k-ascending fp32 FMA chain
// (bit-path identical to previous kernel, absmax 0.0).
template<int KDIM,int ODIM,int UO,bool HAS_BIAS,int MODE,typename TIn>
__global__ __launch_bounds__(256,3)
void sgemm(const TIn* __restrict__ X, const float* __restrict__ Wt,
           const float* __restrict__ bias, const float* __restrict__ bn,
           const float* __restrict__ resid, void* __restrict__ out, float vth)
{
  constexpr int NC   = KDIM/16;       // chunks per t
  constexpr int TOT  = T_*NC;         // total chunks
  constexpr int ESZ  = (int)sizeof(TIn);
  constexpr int ROWB = 256*ESZ;       // LDS row bytes (n-tile = 256)
  constexpr int CHB  = 16*ROWB;       // chunk bytes
  __shared__ __align__(16) uint8_t LB[2*CHB];

  const int tid  = threadIdx.x;
  const int lane = tid & 63;
  const int wid  = __builtin_amdgcn_readfirstlane(tid >> 6);   // wave id, uniform
  const int b    = blockIdx.z;
  const int n0   = blockIdx.x*256;
  const int ow   = blockIdx.y*(4*UO) + wid*UO;                 // uniform o-base

  const uint32_t lbase =
      (uint32_t)(uintptr_t)(__attribute__((address_space(3))) uint8_t*)&LB[0];

  auto stage = [&](int ch){
    const int t = ch/NC, c = ch & (NC-1), pb = ch & 1;
    const TIn* Xb = X + ((size_t)(t*B_+b)*KDIM + c*16)*N_ + n0;
    if constexpr (ESZ==4){
      // 16 rows x 1024B; wave stages rows {wid, wid+4, wid+8, wid+12}
#pragma unroll
      for (int j=0;j<4;j++){
        const int r = wid + 4*j;
        __builtin_amdgcn_global_load_lds(
          (const __attribute__((address_space(1))) void*)(Xb + (size_t)r*N_ + lane*4),
          (__attribute__((address_space(3))) void*)&LB[pb*CHB + r*ROWB], 16, 0, 0);
      }
    } else {
      // 16 rows x 256B; one width-16 instr per wave covers 4 rows
      const int r = 4*wid + (lane>>4);
      __builtin_amdgcn_global_load_lds(
        (const __attribute__((address_space(1))) void*)(Xb + (size_t)r*N_ + (lane&15)*16),
        (__attribute__((address_space(3))) void*)&LB[pb*CHB + 4*wid*ROWB], 16, 0, 0);
    }
  };

  v2f acc[UO][2], vli[UO][2];
#pragma unroll
  for (int i=0;i<UO;i++){ vli[i][0]=(v2f){0.f,0.f}; vli[i][1]=(v2f){0.f,0.f}; }

  WReg<UO> w[2];
  f4v xv[2];
  uint32_t xw[2];

  stage(0);
  __syncthreads();

#pragma unroll 1
  for (int ch=0; ch<TOT; ++ch){
    const int c  = ch & (NC-1);
    const int pb = ch & 1;
    const int kb = c*16;

    if (ch+1 < TOT) stage(ch+1);

    // prologue loads for k=0 of this chunk
    wload<UO>(w[0], Wt + (size_t)kb*ODIM + ow);
    {
      uint32_t la = lbase + pb*CHB + lane*(ESZ*4);
      if constexpr (ESZ==4) asm volatile("ds_read_b128 %0, %1" : "=v"(xv[0]) : "v"(la));
      else                  asm volatile("ds_read_b32 %0, %1"  : "=v"(xw[0]) : "v"(la));
    }

    if (c==0){
#pragma unroll
      for (int i=0;i<UO;i++){ acc[i][0]=(v2f){0.f,0.f}; acc[i][1]=(v2f){0.f,0.f}; }
    }

#pragma unroll
    for (int k=0;k<16;k++){
      asm volatile("s_waitcnt lgkmcnt(0)" ::: "memory");
      __builtin_amdgcn_sched_barrier(0);
      if (k<15){
        const int s = (k+1)&1;
        wload<UO>(w[s], Wt + (size_t)(kb+k+1)*ODIM + ow);
        uint32_t la = lbase + pb*CHB + (k+1)*ROWB + lane*(ESZ*4);
        if constexpr (ESZ==4) asm volatile("ds_read_b128 %0, %1" : "=v"(xv[s]) : "v"(la));
        else                  asm volatile("ds_read_b32 %0, %1"  : "=v"(xw[s]) : "v"(la));
      }
      {
        const int s = k&1;
        v2f xa, xb;
        if constexpr (ESZ==4){
          xa = (v2f){ xv[s][0], xv[s][1] };
          xb = (v2f){ xv[s][2], xv[s][3] };
        } else {
          uint32_t u = xw[s];
          xa = (v2f){ (float)(u & 255u), (float)((u>>8) & 255u) };
          xb = (v2f){ (float)((u>>16) & 255u), (float)(u>>24) };
        }
#pragma unroll
        for (int p=0;p<UO/2;p++){
          PKLs(acc[2*p  ][0], w[s].p[p], xa);
          PKLs(acc[2*p  ][1], w[s].p[p], xb);
          PKHs(acc[2*p+1][0], w[s].p[p], xa);
          PKHs(acc[2*p+1][1], w[s].p[p], xb);
        }
      }
    }

    if (c == NC-1){
      // epilogue for this t: bias -> BN -> LIF -> store (identical formula chain)
      const int t = ch/NC;
#pragma unroll
      for (int i=0;i<UO;i++){
        const int o = ow + i;
        const float g  = bn[o];
        const float be = bn[ODIM + o];
        const float m  = bn[2*ODIM + o];
        const float rs = 1.0f / sqrtf(bn[3*ODIM + o] + 1e-5f);
        const float bi = HAS_BIAS ? bias[o] : 0.0f;
        float sv[4];
#pragma unroll
        for (int jj=0;jj<4;jj++){
          float y  = acc[i][jj>>1][jj&1] + bi;
          float yb = (g*(y - m))*rs + be;
          float vv = vli[i][jj>>1][jj&1];
          vv += (yb - vv)*0.5f;
          float s = (vv >= vth) ? 1.0f : 0.0f;
          vli[i][jj>>1][jj&1] = (s!=0.0f) ? 0.0f : vv;
          sv[jj] = s;
        }
        const size_t base = ((size_t)(t*B_+b)*ODIM + o)*N_ + n0 + 4*lane;
        if (MODE==0){
          uchar4 pa;
          pa.x=(uint8_t)sv[0]; pa.y=(uint8_t)sv[1]; pa.z=(uint8_t)sv[2]; pa.w=(uint8_t)sv[3];
          *(uchar4*)((uint8_t*)out + base) = pa;
        } else {
          const float4 r0 = *(const float4*)&resid[base];
          *(float4*)&((float*)out)[base] =
            make_float4(r0.x+sv[0], r0.y+sv[1], r0.z+sv[2], r0.w+sv[3]);
        }
      }
    }
    __syncthreads();
  }
}

// kv[t,b,h,d,e] = sum_n k[d,n]*v[e,n] over binary byte spikes (exact popc).
__global__ __launch_bounds__(256)
void kv_kernel(const uint8_t* __restrict__ qkv, float* __restrict__ kvout)
{
  int blk = blockIdx.x;          // (t*B+b)*HEADS + h
  int h = blk & 7, tb = blk >> 3;
  int tid = threadIdx.x;
  int e = tid & 31, d0 = (tid >> 5) * 4;
  const uint8_t* kp = qkv + ((size_t)tb*768 + 256 + h*DH_)*N_;
  const uint8_t* vp = qkv + ((size_t)tb*768 + 512 + h*DH_)*N_;
  const uint4* vr = (const uint4*)(vp + (size_t)e*N_);
  const uint4* k0 = (const uint4*)(kp + (size_t)(d0+0)*N_);
  const uint4* k1 = (const uint4*)(kp + (size_t)(d0+1)*N_);
  const uint4* k2 = (const uint4*)(kp + (size_t)(d0+2)*N_);
  const uint4* k3 = (const uint4*)(kp + (size_t)(d0+3)*N_);
  int s0=0,s1=0,s2=0,s3=0;
  for (int q=0;q<N_/16;q++){
    uint4 vv = vr[q];
    uint4 a0 = k0[q], a1 = k1[q], a2 = k2[q], a3 = k3[q];
    s0 += __popc(a0.x&vv.x)+__popc(a0.y&vv.y)+__popc(a0.z&vv.z)+__popc(a0.w&vv.w);
    s1 += __popc(a1.x&vv.x)+__popc(a1.y&vv.y)+__popc(a1.z&vv.z)+__popc(a1.w&vv.w);
    s2 += __popc(a2.x&vv.x)+__popc(a2.y&vv.y)+__popc(a2.z&vv.z)+__popc(a2.w&vv.w);
    s3 += __popc(a3.x&vv.x)+__popc(a3.y&vv.y)+__popc(a3.z&vv.z)+__popc(a3.w&vv.w);
  }
  float* kvp = kvout + (size_t)blk*DH_*DH_;
  kvp[(d0+0)*DH_ + e] = (float)s0;
  kvp[(d0+1)*DH_ + e] = (float)s1;
  kvp[(d0+2)*DH_ + e] = (float)s2;
  kvp[(d0+3)*DH_ + e] = (float)s3;
}

// a[e,n] = 0.125 * sum_d q[d,n]*kv[d,e]; LIF vth=0.5 (exact dyadic).
__global__ __launch_bounds__(256)
void attn_lif_kernel(const uint8_t* __restrict__ qkv, const float* __restrict__ kv,
                     uint8_t* __restrict__ as_)
{
  int tid = threadIdx.x;
  int n = blockIdx.x*256 + tid;
  int h = blockIdx.y, b = blockIdx.z;
  __shared__ float kvL[DH_*DH_];
  float v[DH_];
#pragma unroll
  for (int e=0;e<DH_;e++) v[e]=0.0f;
  for (int t=0;t<T_;t++){
    const float* kvp = kv + ((size_t)((t*B_+b)*HEADS_+h))*DH_*DH_;
    __syncthreads();
#pragma unroll
    for (int r=0;r<4;r++) kvL[tid+256*r] = kvp[tid+256*r];
    __syncthreads();
    const uint8_t* qp = qkv + ((size_t)(t*B_+b)*768 + h*DH_)*N_ + n;
    float qv[DH_];
#pragma unroll
    for (int d=0;d<DH_;d++) qv[d] = (float)qp[(size_t)d*N_];
    uint8_t* op = as_ + ((size_t)(t*B_+b)*C_ + h*DH_)*N_ + n;
#pragma unroll
    for (int e=0;e<DH_;e++){
      float a=0.0f;
#pragma unroll
      for (int d=0;d<DH_;d++) a += qv[d]*kvL[d*DH_+e];
      a *= 0.125f;
      float vv = v[e];
      vv += (a - vv)*0.5f;
      float s = (vv >= 0.5f) ? 1.0f : 0.0f;
      v[e] = (s!=0.0f) ? 0.0f : vv;
      op[(size_t)e*N_] = (uint8_t)s;
    }
  }
}

extern "C" void kernel_launch(void* const* d_in, const int* in_sizes, int n_in,
                              void* d_out, int out_size, void* d_ws, size_t ws_size,
                              hipStream_t stream)
{
  const float* x      = (const float*)d_in[0];
  const float* wq     = (const float*)d_in[2];
  const float* bn_q   = (const float*)d_in[3];
  const float* wk     = (const float*)d_in[4];
  const float* bn_k   = (const float*)d_in[5];
  const float* wv     = (const float*)d_in[6];
  const float* bn_v   = (const float*)d_in[7];
  const float* wproj  = (const float*)d_in[8];
  const float* bproj  = (const float*)d_in[9];
  const float* bnproj = (const float*)d_in[10];
  const float* wfc1   = (const float*)d_in[11];
  const float* bfc1   = (const float*)d_in[12];
  const float* bnfc1  = (const float*)d_in[13];
  const float* wfc2   = (const float*)d_in[14];
  const float* bfc2   = (const float*)d_in[15];
  const float* bnfc2  = (const float*)d_in[16];

  char* ws = (char*)d_ws;
  const size_t TB = (size_t)T_*B_;
  uint8_t* qkv = (uint8_t*)ws;                       // TB*768*N
  uint8_t* as_ = (uint8_t*)ws + TB*768*N_;           // TB*256*N
  uint8_t* h1s = (uint8_t*)ws;                       // TB*1024*N (overlay)
  size_t off = TB*768*N_ + TB*(size_t)C_*N_;
  float* xnew = (float*)(ws + off); off += TB*(size_t)C_*N_*4;
  float* WtQ  = (float*)(ws + off); off += (size_t)C_*768*4;
  float* WtP  = (float*)(ws + off); off += (size_t)C_*C_*4;
  float* WtF1 = (float*)(ws + off); off += (size_t)C_*HD_*4;
  float* WtF2 = (float*)(ws + off); off += (size_t)HD_*C_*4;
  float* bnQ  = (float*)(ws + off); off += 4*768*4;
  float* kvb  = (float*)(ws + off); off += TB*HEADS_*DH_*DH_*4;

  dim3 blk(256);
  transW<<<dim3(8,8),blk,0,stream>>>(wq, WtQ, 256, 256, 768, 0);
  transW<<<dim3(8,8),blk,0,stream>>>(wk, WtQ, 256, 256, 768, 256);
  transW<<<dim3(8,8),blk,0,stream>>>(wv, WtQ, 256, 256, 768, 512);
  transW<<<dim3(8,8),blk,0,stream>>>(wproj, WtP, 256, 256, 256, 0);
  transW<<<dim3(8,32),blk,0,stream>>>(wfc1, WtF1, 1024, 256, 1024, 0);
  transW<<<dim3(32,8),blk,0,stream>>>(wfc2, WtF2, 256, 1024, 256, 0);
  packBn3<<<dim3(4),blk,0,stream>>>(bn_q, bn_k, bn_v, bnQ);

  // fused QKV GEMM -> spikes
  sgemm<C_,768,16,false,0,float><<<dim3(4,12,16),blk,0,stream>>>(
      x, WtQ, nullptr, bnQ, nullptr, qkv, 1.0f);
  kv_kernel<<<dim3(T_*B_*HEADS_),blk,0,stream>>>(qkv, kvb);
  attn_lif_kernel<<<dim3(4,HEADS_,B_),blk,0,stream>>>(qkv, kvb, as_);
  // proj -> xnew = x + attn spike
  sgemm<C_,C_,8,true,1,uint8_t><<<dim3(4,8,16),blk,0,stream>>>(
      as_, WtP, bproj, bnproj, x, xnew, 1.0f);
  // fc1 -> h1 spikes (overlays dead qkv/as_)
  sgemm<C_,HD_,16,true,0,float><<<dim3(4,16,16),blk,0,stream>>>(
      xnew, WtF1, bfc1, bnfc1, nullptr, h1s, 1.0f);
  // fc2 -> out = xnew + mlp spike
  sgemm<HD_,C_,8,true,1,uint8_t><<<dim3(4,8,16),blk,0,stream>>>(
      h1s, WtF2, bfc2, bnfc2, xnew, d_out, 1.0f);
}